// Round 1
// baseline (436.401 us; speedup 1.0000x reference)
//
#include <hip/hip_runtime.h>
#include <hip/hip_bf16.h>
#include <stdint.h>

// HGNN layer: out = dv*(H*(de*(H^T*(dv*x))))*W^T + b
// N=20000 nodes, E=4096 hyperedges, D=128 features. All inputs f32.
// Strategy: degrees in one HBM pass; both big GEMMs in bf16 MFMA (f32 acc);
// dv folded into xTb (pre-transposed bf16), de folded into split-K reduce,
// dv+W-linear fused into GEMM2 epilogue.

#define N_ 20000
#define E_ 4096
#define D_ 128

typedef __attribute__((ext_vector_type(8))) short    bf16x8;   // 8 bf16 (4 VGPR)
typedef __attribute__((ext_vector_type(4))) float    f32x4;
typedef __attribute__((ext_vector_type(8))) unsigned short us8;
typedef __attribute__((ext_vector_type(4))) unsigned short us4;

__device__ __forceinline__ unsigned short f2bf(float f) {
  unsigned u = __float_as_uint(f);
  u += 0x7FFFu + ((u >> 16) & 1u);        // round-to-nearest-even
  return (unsigned short)(u >> 16);
}

// ---------------------------------------------------------------------------
// K1: one pass over H: rowsum -> dv[n] = rs^-1/2 ; colsum -> atomic partial
// 256 blocks x 256 thr; one wave owns rows r = gw + 1024*k.
// Each lane owns columns {4l..4l+3}+256i (i<16) -> 64 colsum regs.
// ---------------------------------------------------------------------------
__global__ __launch_bounds__(256) void k_degrees(const float* __restrict__ H,
                                                 float* __restrict__ dv,
                                                 float* __restrict__ desum) {
  const int lane = threadIdx.x & 63;
  const int gw   = blockIdx.x * 4 + (threadIdx.x >> 6);   // 0..1023
  f32x4 cs[16];
#pragma unroll
  for (int i = 0; i < 16; ++i) cs[i] = (f32x4){0.f, 0.f, 0.f, 0.f};
  for (int r = gw; r < N_; r += 1024) {
    const f32x4* row = (const f32x4*)(H + (size_t)r * E_);
    float rs = 0.f;
#pragma unroll
    for (int i = 0; i < 16; ++i) {
      f32x4 v = row[lane + 64 * i];
      rs += (v.x + v.y) + (v.z + v.w);
      cs[i].x += v.x; cs[i].y += v.y; cs[i].z += v.z; cs[i].w += v.w;
    }
#pragma unroll
    for (int off = 32; off; off >>= 1) rs += __shfl_xor(rs, off);
    if (lane == 0) dv[r] = rs > 0.f ? rsqrtf(rs) : 0.f;
  }
#pragma unroll
  for (int i = 0; i < 16; ++i) {
    int c = 4 * (lane + 64 * i);
    atomicAdd(&desum[c + 0], cs[i].x);
    atomicAdd(&desum[c + 1], cs[i].y);
    atomicAdd(&desum[c + 2], cs[i].z);
    atomicAdd(&desum[c + 3], cs[i].w);
  }
}

// K1b: de[e] = colsum>0 ? 1/colsum : 0
__global__ __launch_bounds__(256) void k_fin(const float* __restrict__ desum,
                                             float* __restrict__ de) {
  int e = blockIdx.x * 256 + threadIdx.x;   // grid 16 -> 4096
  float s = desum[e];
  de[e] = s > 0.f ? 1.f / s : 0.f;
}

// ---------------------------------------------------------------------------
// K0: xTb[d][n] = bf16(dv[n] * x[n][d])   (transpose via LDS tile)
// grid 313 blocks, 64 n-rows each.
// ---------------------------------------------------------------------------
__global__ __launch_bounds__(256) void k_xT(const float* __restrict__ x,
                                            const float* __restrict__ dv,
                                            unsigned short* __restrict__ xTb) {
  __shared__ float tile[64 * 132];          // [n][d], pad 132
  const int t  = threadIdx.x;
  const int n0 = blockIdx.x * 64;
#pragma unroll
  for (int it = 0; it < 8; ++it) {
    int n  = it * 8 + (t >> 5);
    int d4 = (t & 31) * 4;
    int nn = min(n0 + n, N_ - 1);
    *(float4*)&tile[n * 132 + d4] = *(const float4*)(x + (size_t)nn * D_ + d4);
  }
  __syncthreads();
  const int c     = t & 7;                  // n-chunk of 8
  const int dbase = t >> 3;                 // 0..31
  float dvv[8];
#pragma unroll
  for (int i = 0; i < 8; ++i) dvv[i] = dv[min(n0 + c * 8 + i, N_ - 1)];
  bool ok = (n0 + c * 8) < N_;              // 20000 % 8 == 0 -> chunks never split
#pragma unroll
  for (int jj = 0; jj < 4; ++jj) {
    int d = dbase + jj * 32;
    union { us8 v; unsigned short u[8]; } un;
#pragma unroll
    for (int i = 0; i < 8; ++i) un.u[i] = f2bf(tile[(c * 8 + i) * 132 + d] * dvv[i]);
    if (ok) *(us8*)(xTb + (size_t)d * N_ + n0 + c * 8) = un.v;
  }
}

// KW: Wb = bf16(W), [j][d] row-major
__global__ __launch_bounds__(256) void k_wb(const float* __restrict__ W,
                                            unsigned short* __restrict__ Wb) {
  int tid = blockIdx.x * 256 + threadIdx.x; // grid 16 -> 4096, 4 elems each
  float4 v = *(const float4*)(W + (size_t)tid * 4);
  union { us4 v; unsigned short u[4]; } un;
  un.u[0] = f2bf(v.x); un.u[1] = f2bf(v.y); un.u[2] = f2bf(v.z); un.u[3] = f2bf(v.w);
  *(us4*)(Wb + (size_t)tid * 4) = un.v;
}

// ---------------------------------------------------------------------------
// GEMM1: partialT[s][d][e] = sum_{n in chunk s} H[n][e] * xdv[n][d]
// block: 64 e x 128 d, BK=32. A = H^T tile: reg-staged with transposed,
// XOR-swizzled ds_write_b128 (write: all lanes same k-block -> swizzle by m&3
// spreads 16B blocks across all banks; reads use same swizzle).
// grid = 64 e-blocks * 8 K-chunks = 512.
// ---------------------------------------------------------------------------
__global__ __launch_bounds__(256) void k_gemm1(const float* __restrict__ H,
                                               const unsigned short* __restrict__ xTb,
                                               float* __restrict__ partialT) {
  __shared__ unsigned short lA[64 * 32];    // swizzled [m(e)][k(n)]
  __shared__ unsigned short lB[128 * 32];   // [d][k] linear
  const int t    = threadIdx.x;
  const int lane = t & 63;
  const int wid  = t >> 6;
  const int eb   = blockIdx.x & 63;
  const int s    = blockIdx.x >> 6;         // 0..7
  const int e0   = eb * 64;
  const int k0   = (s * 625) / 8;           // 625 K-steps total (625*32 = 20000)
  const int k1   = ((s + 1) * 625) / 8;

  f32x4 acc[2][4];
#pragma unroll
  for (int i = 0; i < 2; ++i)
#pragma unroll
    for (int j = 0; j < 4; ++j) acc[i][j] = (f32x4){0.f, 0.f, 0.f, 0.f};

  const int wy = wid >> 1, wx = wid & 1;    // wave tile: 32 e x 64 d
  const int am = t & 63;                    // A-stage: m
  const int aw = t >> 6;                    // A-stage: k-block (k = aw*8+j)

  for (int step = k0; step < k1; ++step) {
    const int n0 = step * 32;
    __syncthreads();
    // B stage: [128 d][32 n] from xTb (K-contiguous), 16 elems/thread
    {
      int d = t >> 1, nb = (t & 1) * 16;
      const us8* src = (const us8*)(xTb + (size_t)d * N_ + n0 + nb);
      us8 v0 = src[0], v1 = src[1];
      *(us8*)&lB[d * 32 + nb]     = v0;
      *(us8*)&lB[d * 32 + nb + 8] = v1;
    }
    // A stage: 8 coalesced scalar loads down k, cvt, swizzled b128 write
    {
      const float* src = H + (size_t)(n0 + aw * 8) * E_ + e0 + am;
      union { bf16x8 v; unsigned short u[8]; } un;
#pragma unroll
      for (int j = 0; j < 8; ++j) un.u[j] = f2bf(src[(size_t)j * E_]);
      *(bf16x8*)&lA[(am << 5) + ((aw ^ (am & 3)) << 3)] = un.v;
    }
    __syncthreads();
    const int kg = lane >> 4;
    bf16x8 af[2], bf[4];
#pragma unroll
    for (int mi = 0; mi < 2; ++mi) {
      int m = wy * 32 + mi * 16 + (lane & 15);
      af[mi] = *(const bf16x8*)&lA[(m << 5) + ((kg ^ (m & 3)) << 3)];
    }
#pragma unroll
    for (int ni = 0; ni < 4; ++ni) {
      int d = wx * 64 + ni * 16 + (lane & 15);
      bf[ni] = *(const bf16x8*)&lB[(d << 5) + (kg << 3)];
    }
#pragma unroll
    for (int mi = 0; mi < 2; ++mi)
#pragma unroll
      for (int ni = 0; ni < 4; ++ni)
        acc[mi][ni] = __builtin_amdgcn_mfma_f32_16x16x32_bf16(af[mi], bf[ni], acc[mi][ni], 0, 0, 0);
  }
  // epilogue: D row = e, col = d (C/D: col=lane&15, row=(lane>>4)*4+reg)
#pragma unroll
  for (int mi = 0; mi < 2; ++mi)
#pragma unroll
    for (int ni = 0; ni < 4; ++ni)
#pragma unroll
      for (int r = 0; r < 4; ++r) {
        int e = e0 + wy * 32 + mi * 16 + (lane >> 4) * 4 + r;
        int d = wx * 64 + ni * 16 + (lane & 15);
        partialT[((size_t)s * 128 + d) * E_ + e] = acc[mi][ni][r];
      }
}

// K3b: x3T[d][e] = bf16(de[e] * sum_s partialT[s][d][e])
__global__ __launch_bounds__(256) void k_reduce1(const float* __restrict__ partialT,
                                                 const float* __restrict__ de,
                                                 unsigned short* __restrict__ x3T) {
  int tid = blockIdx.x * 256 + threadIdx.x;  // grid 2048 -> 524288 = 128*4096
  int d = tid >> 12, e = tid & 4095;
  float s = 0.f;
#pragma unroll
  for (int ss = 0; ss < 8; ++ss) s += partialT[((size_t)ss * 128 + d) * E_ + e];
  x3T[(size_t)d * E_ + e] = f2bf(de[e] * s);
}

// ---------------------------------------------------------------------------
// GEMM2: out[n][j] = (dv[n] * sum_e H[n][e]*x3[e][d]) @ W^T + b
// block: 64 n x 128 d, BK=32, K=4096. Epilogue: dv-scale -> bf16 -> LDS
// round-trip -> 128x128 W MFMA -> +bias -> store. grid 313 (last block ragged).
// ---------------------------------------------------------------------------
__global__ __launch_bounds__(256) void k_gemm2(const float* __restrict__ H,
                                               const unsigned short* __restrict__ x3T,
                                               const unsigned short* __restrict__ Wb,
                                               const float* __restrict__ dv,
                                               const float* __restrict__ bias,
                                               float* __restrict__ out) {
  __shared__ unsigned short lW[128 * 128];  // 32 KB [j][d]
  __shared__ unsigned short sm[64 * 128];   // stA(2048) | stB(4096); reused as lC(8192)
  unsigned short* stA = sm;
  unsigned short* stB = sm + 64 * 32;
  unsigned short* lC  = sm;
  const int t = threadIdx.x, lane = t & 63, wid = t >> 6;
  const int n0b = blockIdx.x * 64;
  const int wy = wid >> 1, wx = wid & 1;    // wave tile: 32 n x 64 d

  // stage W tile once: 64 elems/thread
  {
    int j = t >> 1;
#pragma unroll
    for (int jj = 0; jj < 4; ++jj) {
      int dofs = (t & 1) * 64 + jj * 16;
      const us8* src = (const us8*)(Wb + (size_t)j * 128 + dofs);
      *(us8*)&lW[j * 128 + dofs]     = src[0];
      *(us8*)&lW[j * 128 + dofs + 8] = src[1];
    }
  }

  f32x4 acc[2][4];
#pragma unroll
  for (int i = 0; i < 2; ++i)
#pragma unroll
    for (int j = 0; j < 4; ++j) acc[i][j] = (f32x4){0.f, 0.f, 0.f, 0.f};

  for (int step = 0; step < 128; ++step) {
    const int e0 = step * 32;
    __syncthreads();
    // B stage: [128 d][32 e] from x3T
    {
      int d = t >> 1, ebb = (t & 1) * 16;
      const us8* src = (const us8*)(x3T + (size_t)d * E_ + e0 + ebb);
      us8 v0 = src[0], v1 = src[1];
      *(us8*)&stB[d * 32 + ebb]     = v0;
      *(us8*)&stB[d * 32 + ebb + 8] = v1;
    }
    // A stage: [64 n][32 e] from H (K-contiguous), cvt f32->bf16
    {
      int nr = t >> 2, e8 = (t & 3) * 8;
      int nn = min(n0b + nr, N_ - 1);
      const float* src = H + (size_t)nn * E_ + e0 + e8;
      float4 v0 = *(const float4*)src;
      float4 v1 = *(const float4*)(src + 4);
      union { bf16x8 v; unsigned short u[8]; } un;
      un.u[0] = f2bf(v0.x); un.u[1] = f2bf(v0.y); un.u[2] = f2bf(v0.z); un.u[3] = f2bf(v0.w);
      un.u[4] = f2bf(v1.x); un.u[5] = f2bf(v1.y); un.u[6] = f2bf(v1.z); un.u[7] = f2bf(v1.w);
      *(bf16x8*)&stA[nr * 32 + e8] = un.v;
    }
    __syncthreads();
    const int kg = lane >> 4;
    bf16x8 af[2], bf[4];
#pragma unroll
    for (int mi = 0; mi < 2; ++mi) {
      int m = wy * 32 + mi * 16 + (lane & 15);
      af[mi] = *(const bf16x8*)&stA[m * 32 + kg * 8];
    }
#pragma unroll
    for (int ni = 0; ni < 4; ++ni) {
      int d = wx * 64 + ni * 16 + (lane & 15);
      bf[ni] = *(const bf16x8*)&stB[d * 32 + kg * 8];
    }
#pragma unroll
    for (int mi = 0; mi < 2; ++mi)
#pragma unroll
      for (int ni = 0; ni < 4; ++ni)
        acc[mi][ni] = __builtin_amdgcn_mfma_f32_16x16x32_bf16(af[mi], bf[ni], acc[mi][ni], 0, 0, 0);
  }
  __syncthreads();                          // all frag reads done before lC overwrite
  // dv-scale, cvt bf16, write C2 tile to LDS [64 n][128 d]
#pragma unroll
  for (int mi = 0; mi < 2; ++mi) {
    float dvv[4];
#pragma unroll
    for (int r = 0; r < 4; ++r)
      dvv[r] = dv[min(n0b + wy * 32 + mi * 16 + (lane >> 4) * 4 + r, N_ - 1)];
#pragma unroll
    for (int ni = 0; ni < 4; ++ni)
#pragma unroll
      for (int r = 0; r < 4; ++r) {
        int row = wy * 32 + mi * 16 + (lane >> 4) * 4 + r;
        int col = wx * 64 + ni * 16 + (lane & 15);
        lC[row * 128 + col] = f2bf(acc[mi][ni][r] * dvv[r]);
      }
  }
  __syncthreads();
  // fused linear: out = C2dv @ W^T + b  (K = 128, 4 K-steps)
  f32x4 acc2[2][4];
#pragma unroll
  for (int i = 0; i < 2; ++i)
#pragma unroll
    for (int j = 0; j < 4; ++j) acc2[i][j] = (f32x4){0.f, 0.f, 0.f, 0.f};
#pragma unroll
  for (int ks = 0; ks < 4; ++ks) {
    int kofs = ks * 32 + (lane >> 4) * 8;
    bf16x8 a2[2], b2[4];
#pragma unroll
    for (int mi = 0; mi < 2; ++mi) {
      int m = wy * 32 + mi * 16 + (lane & 15);
      a2[mi] = *(const bf16x8*)&lC[m * 128 + kofs];
    }
#pragma unroll
    for (int ni = 0; ni < 4; ++ni) {
      int j = wx * 64 + ni * 16 + (lane & 15);
      b2[ni] = *(const bf16x8*)&lW[j * 128 + kofs];
    }
#pragma unroll
    for (int mi = 0; mi < 2; ++mi)
#pragma unroll
      for (int ni = 0; ni < 4; ++ni)
        acc2[mi][ni] = __builtin_amdgcn_mfma_f32_16x16x32_bf16(a2[mi], b2[ni], acc2[mi][ni], 0, 0, 0);
  }
#pragma unroll
  for (int mi = 0; mi < 2; ++mi)
#pragma unroll
    for (int ni = 0; ni < 4; ++ni) {
      int j = wx * 64 + ni * 16 + (lane & 15);
      float bb = bias[j];
#pragma unroll
      for (int r = 0; r < 4; ++r) {
        int n = n0b + wy * 32 + mi * 16 + (lane >> 4) * 4 + r;
        if (n < N_) out[(size_t)n * D_ + j] = acc2[mi][ni][r] + bb;
      }
    }
}

// ---------------------------------------------------------------------------
extern "C" void kernel_launch(void* const* d_in, const int* in_sizes, int n_in,
                              void* d_out, int out_size, void* d_ws, size_t ws_size,
                              hipStream_t stream) {
  const float* x = (const float*)d_in[0];
  const float* H = (const float*)d_in[1];
  const float* W = (const float*)d_in[2];
  const float* b = (const float*)d_in[3];
  float* out = (float*)d_out;
  char* ws = (char*)d_ws;
  // workspace layout (all 16B-aligned); total ~23.1 MB
  float*          desum    = (float*)(ws);                    // 16384 B
  float*          de       = (float*)(ws + 16384);            // 16384 B
  float*          dv       = (float*)(ws + 32768);            // 80000 -> pad 80128
  unsigned short* Wb       = (unsigned short*)(ws + 112896);  // 32768 B
  unsigned short* xTb      = (unsigned short*)(ws + 145664);  // 5,120,000 B
  unsigned short* x3T      = (unsigned short*)(ws + 5265664); // 1,048,576 B
  float*          partialT = (float*)(ws + 6314240);          // 16,777,216 B

  hipMemsetAsync(desum, 0, 16384, stream);
  k_degrees<<<256, 256, 0, stream>>>(H, dv, desum);
  k_fin<<<16, 256, 0, stream>>>(desum, de);
  k_xT<<<313, 256, 0, stream>>>(x, dv, xTb);
  k_wb<<<16, 256, 0, stream>>>(W, Wb);
  k_gemm1<<<512, 256, 0, stream>>>(H, xTb, partialT);
  k_reduce1<<<2048, 256, 0, stream>>>(partialT, de, x3T);
  k_gemm2<<<313, 256, 0, stream>>>(H, x3T, Wb, dv, b, out);
}

// Round 2
// 312.146 us; speedup vs baseline: 1.3981x; 1.3981x over previous
//
#include <hip/hip_runtime.h>
#include <hip/hip_bf16.h>
#include <stdint.h>

// HGNN layer: out = dv*(H*(de*(H^T*(dv*x))))*W^T + b
// N=20000 nodes, E=4096 hyperedges, D=128 features. All inputs f32.
// R2: rowsum pass rewritten for occupancy (2500 blocks, no atomics);
// colsum (de) folded into GEMM1's A-stage for free.

#define N_ 20000
#define E_ 4096
#define D_ 128

typedef __attribute__((ext_vector_type(8))) short    bf16x8;   // 8 bf16 (4 VGPR)
typedef __attribute__((ext_vector_type(4))) float    f32x4;
typedef __attribute__((ext_vector_type(8))) unsigned short us8;
typedef __attribute__((ext_vector_type(4))) unsigned short us4;

__device__ __forceinline__ unsigned short f2bf(float f) {
  unsigned u = __float_as_uint(f);
  u += 0x7FFFu + ((u >> 16) & 1u);        // round-to-nearest-even
  return (unsigned short)(u >> 16);
}

// ---------------------------------------------------------------------------
// K1: rowsum only -> dv[n] = rs^-1/2.  2500 blocks x 256 thr, 8 rows/block.
// Thread t reads cols {t*4..t*4+3} + 1024j (j<4) of each row: coalesced 4KB
// per (row, j) group. Wave shfl-reduce + LDS cross-wave combine.
// ---------------------------------------------------------------------------
__global__ __launch_bounds__(256) void k_rowsum(const float* __restrict__ H,
                                                float* __restrict__ dv) {
  __shared__ float red[32];
  const int t = threadIdx.x;
  const int lane = t & 63, w = t >> 6;
  const size_t base = (size_t)blockIdx.x * 8 * E_;
  float rs[8];
#pragma unroll
  for (int r = 0; r < 8; ++r) {
    const float* rp = H + base + (size_t)r * E_ + t * 4;
    f32x4 v0 = *(const f32x4*)(rp);
    f32x4 v1 = *(const f32x4*)(rp + 1024);
    f32x4 v2 = *(const f32x4*)(rp + 2048);
    f32x4 v3 = *(const f32x4*)(rp + 3072);
    f32x4 s = (v0 + v1) + (v2 + v3);
    rs[r] = (s.x + s.y) + (s.z + s.w);
  }
#pragma unroll
  for (int r = 0; r < 8; ++r)
#pragma unroll
    for (int off = 32; off; off >>= 1) rs[r] += __shfl_xor(rs[r], off);
  if (lane == 0) {
#pragma unroll
    for (int r = 0; r < 8; ++r) red[w * 8 + r] = rs[r];
  }
  __syncthreads();
  if (t < 8) {
    float s = red[t] + red[8 + t] + red[16 + t] + red[24 + t];
    dv[blockIdx.x * 8 + t] = s > 0.f ? rsqrtf(s) : 0.f;
  }
}

// K1b: de[e] = colsum>0 ? 1/colsum : 0   (runs AFTER gemm1, which fills desum)
__global__ __launch_bounds__(256) void k_fin(const float* __restrict__ desum,
                                             float* __restrict__ de) {
  int e = blockIdx.x * 256 + threadIdx.x;   // grid 16 -> 4096
  float s = desum[e];
  de[e] = s > 0.f ? 1.f / s : 0.f;
}

// ---------------------------------------------------------------------------
// K0: xTb[d][n] = bf16(dv[n] * x[n][d])   (transpose via LDS tile)
// grid 313 blocks, 64 n-rows each.
// ---------------------------------------------------------------------------
__global__ __launch_bounds__(256) void k_xT(const float* __restrict__ x,
                                            const float* __restrict__ dv,
                                            unsigned short* __restrict__ xTb) {
  __shared__ float tile[64 * 132];          // [n][d], pad 132
  const int t  = threadIdx.x;
  const int n0 = blockIdx.x * 64;
#pragma unroll
  for (int it = 0; it < 8; ++it) {
    int n  = it * 8 + (t >> 5);
    int d4 = (t & 31) * 4;
    int nn = min(n0 + n, N_ - 1);
    *(float4*)&tile[n * 132 + d4] = *(const float4*)(x + (size_t)nn * D_ + d4);
  }
  __syncthreads();
  const int c     = t & 7;                  // n-chunk of 8
  const int dbase = t >> 3;                 // 0..31
  float dvv[8];
#pragma unroll
  for (int i = 0; i < 8; ++i) dvv[i] = dv[min(n0 + c * 8 + i, N_ - 1)];
  bool ok = (n0 + c * 8) < N_;              // 20000 % 8 == 0 -> chunks never split
#pragma unroll
  for (int jj = 0; jj < 4; ++jj) {
    int d = dbase + jj * 32;
    union { us8 v; unsigned short u[8]; } un;
#pragma unroll
    for (int i = 0; i < 8; ++i) un.u[i] = f2bf(tile[(c * 8 + i) * 132 + d] * dvv[i]);
    if (ok) *(us8*)(xTb + (size_t)d * N_ + n0 + c * 8) = un.v;
  }
}

// KW: Wb = bf16(W), [j][d] row-major
__global__ __launch_bounds__(256) void k_wb(const float* __restrict__ W,
                                            unsigned short* __restrict__ Wb) {
  int tid = blockIdx.x * 256 + threadIdx.x; // grid 16 -> 4096, 4 elems each
  float4 v = *(const float4*)(W + (size_t)tid * 4);
  union { us4 v; unsigned short u[4]; } un;
  un.u[0] = f2bf(v.x); un.u[1] = f2bf(v.y); un.u[2] = f2bf(v.z); un.u[3] = f2bf(v.w);
  *(us4*)(Wb + (size_t)tid * 4) = un.v;
}

// ---------------------------------------------------------------------------
// GEMM1: partialT[s][d][e] = sum_{n in chunk s} H[n][e] * xdv[n][d]
// block: 64 e x 128 d, BK=32. A = H^T tile: reg-staged with transposed,
// XOR-swizzled ds_write_b128. Colsum of H accumulated as a byproduct of the
// A-stage (each H element loaded exactly once across the grid) -> desum.
// grid = 64 e-blocks * 8 K-chunks = 512.
// ---------------------------------------------------------------------------
__global__ __launch_bounds__(256) void k_gemm1(const float* __restrict__ H,
                                               const unsigned short* __restrict__ xTb,
                                               float* __restrict__ partialT,
                                               float* __restrict__ desum) {
  __shared__ unsigned short lA[64 * 32];    // swizzled [m(e)][k(n)]
  __shared__ unsigned short lB[128 * 32];   // [d][k] linear
  __shared__ float csr[256];
  const int t    = threadIdx.x;
  const int lane = t & 63;
  const int wid  = t >> 6;
  const int eb   = blockIdx.x & 63;
  const int s    = blockIdx.x >> 6;         // 0..7
  const int e0   = eb * 64;
  const int k0   = (s * 625) / 8;           // 625 K-steps total (625*32 = 20000)
  const int k1   = ((s + 1) * 625) / 8;

  f32x4 acc[2][4];
#pragma unroll
  for (int i = 0; i < 2; ++i)
#pragma unroll
    for (int j = 0; j < 4; ++j) acc[i][j] = (f32x4){0.f, 0.f, 0.f, 0.f};

  const int wy = wid >> 1, wx = wid & 1;    // wave tile: 32 e x 64 d
  const int am = t & 63;                    // A-stage: m (column e0+am)
  const int aw = t >> 6;                    // A-stage: k-block (k = aw*8+j)
  float cacc = 0.f;                         // running colsum partial

  for (int step = k0; step < k1; ++step) {
    const int n0 = step * 32;
    __syncthreads();
    // B stage: [128 d][32 n] from xTb (K-contiguous), 16 elems/thread
    {
      int d = t >> 1, nb = (t & 1) * 16;
      const us8* src = (const us8*)(xTb + (size_t)d * N_ + n0 + nb);
      us8 v0 = src[0], v1 = src[1];
      *(us8*)&lB[d * 32 + nb]     = v0;
      *(us8*)&lB[d * 32 + nb + 8] = v1;
    }
    // A stage: 8 coalesced scalar loads down k, cvt, swizzled b128 write
    {
      const float* src = H + (size_t)(n0 + aw * 8) * E_ + e0 + am;
      union { bf16x8 v; unsigned short u[8]; } un;
#pragma unroll
      for (int j = 0; j < 8; ++j) {
        float fv = src[(size_t)j * E_];
        cacc += fv;
        un.u[j] = f2bf(fv);
      }
      *(bf16x8*)&lA[(am << 5) + ((aw ^ (am & 3)) << 3)] = un.v;
    }
    __syncthreads();
    const int kg = lane >> 4;
    bf16x8 af[2], bf[4];
#pragma unroll
    for (int mi = 0; mi < 2; ++mi) {
      int m = wy * 32 + mi * 16 + (lane & 15);
      af[mi] = *(const bf16x8*)&lA[(m << 5) + ((kg ^ (m & 3)) << 3)];
    }
#pragma unroll
    for (int ni = 0; ni < 4; ++ni) {
      int d = wx * 64 + ni * 16 + (lane & 15);
      bf[ni] = *(const bf16x8*)&lB[(d << 5) + (kg << 3)];
    }
#pragma unroll
    for (int mi = 0; mi < 2; ++mi)
#pragma unroll
      for (int ni = 0; ni < 4; ++ni)
        acc[mi][ni] = __builtin_amdgcn_mfma_f32_16x16x32_bf16(af[mi], bf[ni], acc[mi][ni], 0, 0, 0);
  }
  // colsum flush: 4 wave-partials per column -> LDS -> 64 atomics/block
  csr[t] = cacc;
  __syncthreads();
  if (t < 64) {
    float s4 = csr[t] + csr[64 + t] + csr[128 + t] + csr[192 + t];
    atomicAdd(&desum[e0 + t], s4);
  }
  // epilogue: D row = e, col = d (C/D: col=lane&15, row=(lane>>4)*4+reg)
#pragma unroll
  for (int mi = 0; mi < 2; ++mi)
#pragma unroll
    for (int ni = 0; ni < 4; ++ni)
#pragma unroll
      for (int r = 0; r < 4; ++r) {
        int e = e0 + wy * 32 + mi * 16 + (lane >> 4) * 4 + r;
        int d = wx * 64 + ni * 16 + (lane & 15);
        partialT[((size_t)s * 128 + d) * E_ + e] = acc[mi][ni][r];
      }
}

// K3b: x3T[d][e] = bf16(de[e] * sum_s partialT[s][d][e])
__global__ __launch_bounds__(256) void k_reduce1(const float* __restrict__ partialT,
                                                 const float* __restrict__ de,
                                                 unsigned short* __restrict__ x3T) {
  int tid = blockIdx.x * 256 + threadIdx.x;  // grid 2048 -> 524288 = 128*4096
  int d = tid >> 12, e = tid & 4095;
  float s = 0.f;
#pragma unroll
  for (int ss = 0; ss < 8; ++ss) s += partialT[((size_t)ss * 128 + d) * E_ + e];
  x3T[(size_t)d * E_ + e] = f2bf(de[e] * s);
}

// ---------------------------------------------------------------------------
// GEMM2: out[n][j] = (dv[n] * sum_e H[n][e]*x3[e][d]) @ W^T + b
// block: 64 n x 128 d, BK=32, K=4096. Epilogue: dv-scale -> bf16 -> LDS
// round-trip -> 128x128 W MFMA -> +bias -> store. grid 313 (last block ragged).
// ---------------------------------------------------------------------------
__global__ __launch_bounds__(256) void k_gemm2(const float* __restrict__ H,
                                               const unsigned short* __restrict__ x3T,
                                               const unsigned short* __restrict__ Wb,
                                               const float* __restrict__ dv,
                                               const float* __restrict__ bias,
                                               float* __restrict__ out) {
  __shared__ unsigned short lW[128 * 128];  // 32 KB [j][d]
  __shared__ unsigned short sm[64 * 128];   // stA(2048) | stB(4096); reused as lC(8192)
  unsigned short* stA = sm;
  unsigned short* stB = sm + 64 * 32;
  unsigned short* lC  = sm;
  const int t = threadIdx.x, lane = t & 63, wid = t >> 6;
  const int n0b = blockIdx.x * 64;
  const int wy = wid >> 1, wx = wid & 1;    // wave tile: 32 n x 64 d

  // stage W tile once: 64 elems/thread
  {
    int j = t >> 1;
#pragma unroll
    for (int jj = 0; jj < 4; ++jj) {
      int dofs = (t & 1) * 64 + jj * 16;
      const us8* src = (const us8*)(Wb + (size_t)j * 128 + dofs);
      *(us8*)&lW[j * 128 + dofs]     = src[0];
      *(us8*)&lW[j * 128 + dofs + 8] = src[1];
    }
  }

  f32x4 acc[2][4];
#pragma unroll
  for (int i = 0; i < 2; ++i)
#pragma unroll
    for (int j = 0; j < 4; ++j) acc[i][j] = (f32x4){0.f, 0.f, 0.f, 0.f};

  for (int step = 0; step < 128; ++step) {
    const int e0 = step * 32;
    __syncthreads();
    // B stage: [128 d][32 e] from x3T
    {
      int d = t >> 1, ebb = (t & 1) * 16;
      const us8* src = (const us8*)(x3T + (size_t)d * E_ + e0 + ebb);
      us8 v0 = src[0], v1 = src[1];
      *(us8*)&stB[d * 32 + ebb]     = v0;
      *(us8*)&stB[d * 32 + ebb + 8] = v1;
    }
    // A stage: [64 n][32 e] from H (K-contiguous), cvt f32->bf16
    {
      int nr = t >> 2, e8 = (t & 3) * 8;
      int nn = min(n0b + nr, N_ - 1);
      const float* src = H + (size_t)nn * E_ + e0 + e8;
      float4 v0 = *(const float4*)src;
      float4 v1 = *(const float4*)(src + 4);
      union { bf16x8 v; unsigned short u[8]; } un;
      un.u[0] = f2bf(v0.x); un.u[1] = f2bf(v0.y); un.u[2] = f2bf(v0.z); un.u[3] = f2bf(v0.w);
      un.u[4] = f2bf(v1.x); un.u[5] = f2bf(v1.y); un.u[6] = f2bf(v1.z); un.u[7] = f2bf(v1.w);
      *(bf16x8*)&stA[nr * 32 + e8] = un.v;
    }
    __syncthreads();
    const int kg = lane >> 4;
    bf16x8 af[2], bf[4];
#pragma unroll
    for (int mi = 0; mi < 2; ++mi) {
      int m = wy * 32 + mi * 16 + (lane & 15);
      af[mi] = *(const bf16x8*)&stA[m * 32 + kg * 8];
    }
#pragma unroll
    for (int ni = 0; ni < 4; ++ni) {
      int d = wx * 64 + ni * 16 + (lane & 15);
      bf[ni] = *(const bf16x8*)&stB[d * 32 + kg * 8];
    }
#pragma unroll
    for (int mi = 0; mi < 2; ++mi)
#pragma unroll
      for (int ni = 0; ni < 4; ++ni)
        acc[mi][ni] = __builtin_amdgcn_mfma_f32_16x16x32_bf16(af[mi], bf[ni], acc[mi][ni], 0, 0, 0);
  }
  __syncthreads();                          // all frag reads done before lC overwrite
  // dv-scale, cvt bf16, write C2 tile to LDS [64 n][128 d]
#pragma unroll
  for (int mi = 0; mi < 2; ++mi) {
    float dvv[4];
#pragma unroll
    for (int r = 0; r < 4; ++r)
      dvv[r] = dv[min(n0b + wy * 32 + mi * 16 + (lane >> 4) * 4 + r, N_ - 1)];
#pragma unroll
    for (int ni = 0; ni < 4; ++ni)
#pragma unroll
      for (int r = 0; r < 4; ++r) {
        int row = wy * 32 + mi * 16 + (lane >> 4) * 4 + r;
        int col = wx * 64 + ni * 16 + (lane & 15);
        lC[row * 128 + col] = f2bf(acc[mi][ni][r] * dvv[r]);
      }
  }
  __syncthreads();
  // fused linear: out = C2dv @ W^T + b  (K = 128, 4 K-steps)
  f32x4 acc2[2][4];
#pragma unroll
  for (int i = 0; i < 2; ++i)
#pragma unroll
    for (int j = 0; j < 4; ++j) acc2[i][j] = (f32x4){0.f, 0.f, 0.f, 0.f};
#pragma unroll
  for (int ks = 0; ks < 4; ++ks) {
    int kofs = ks * 32 + (lane >> 4) * 8;
    bf16x8 a2[2], b2[4];
#pragma unroll
    for (int mi = 0; mi < 2; ++mi) {
      int m = wy * 32 + mi * 16 + (lane & 15);
      a2[mi] = *(const bf16x8*)&lC[m * 128 + kofs];
    }
#pragma unroll
    for (int ni = 0; ni < 4; ++ni) {
      int j = wx * 64 + ni * 16 + (lane & 15);
      b2[ni] = *(const bf16x8*)&lW[j * 128 + kofs];
    }
#pragma unroll
    for (int mi = 0; mi < 2; ++mi)
#pragma unroll
      for (int ni = 0; ni < 4; ++ni)
        acc2[mi][ni] = __builtin_amdgcn_mfma_f32_16x16x32_bf16(a2[mi], b2[ni], acc2[mi][ni], 0, 0, 0);
  }
#pragma unroll
  for (int mi = 0; mi < 2; ++mi)
#pragma unroll
    for (int ni = 0; ni < 4; ++ni) {
      int j = wx * 64 + ni * 16 + (lane & 15);
      float bb = bias[j];
#pragma unroll
      for (int r = 0; r < 4; ++r) {
        int n = n0b + wy * 32 + mi * 16 + (lane >> 4) * 4 + r;
        if (n < N_) out[(size_t)n * D_ + j] = acc2[mi][ni][r] + bb;
      }
    }
}

// ---------------------------------------------------------------------------
extern "C" void kernel_launch(void* const* d_in, const int* in_sizes, int n_in,
                              void* d_out, int out_size, void* d_ws, size_t ws_size,
                              hipStream_t stream) {
  const float* x = (const float*)d_in[0];
  const float* H = (const float*)d_in[1];
  const float* W = (const float*)d_in[2];
  const float* b = (const float*)d_in[3];
  float* out = (float*)d_out;
  char* ws = (char*)d_ws;
  // workspace layout (all 16B-aligned); total ~23.1 MB
  float*          desum    = (float*)(ws);                    // 16384 B
  float*          de       = (float*)(ws + 16384);            // 16384 B
  float*          dv       = (float*)(ws + 32768);            // 80000 -> pad 80128
  unsigned short* Wb       = (unsigned short*)(ws + 112896);  // 32768 B
  unsigned short* xTb      = (unsigned short*)(ws + 145664);  // 5,120,000 B
  unsigned short* x3T      = (unsigned short*)(ws + 5265664); // 1,048,576 B
  float*          partialT = (float*)(ws + 6314240);          // 16,777,216 B

  hipMemsetAsync(desum, 0, 16384, stream);
  k_rowsum<<<2500, 256, 0, stream>>>(H, dv);
  k_xT<<<313, 256, 0, stream>>>(x, dv, xTb);
  k_wb<<<16, 256, 0, stream>>>(W, Wb);
  k_gemm1<<<512, 256, 0, stream>>>(H, xTb, partialT, desum);
  k_fin<<<16, 256, 0, stream>>>(desum, de);
  k_reduce1<<<2048, 256, 0, stream>>>(partialT, de, x3T);
  k_gemm2<<<313, 256, 0, stream>>>(H, x3T, Wb, dv, b, out);
}